// Round 6
// baseline (399.955 us; speedup 1.0000x reference)
//
#include <hip/hip_runtime.h>
#include <math.h>

// Bahdanau attention, B=32, T=2048, D=512, U=512, fp32 in/out.
// Round 6: barrier-free K-loop. Block = 32 rows x ALL 512 u. A (32x512 f16,
// rows padded to 520) staged once to LDS in a prologue; K-loop streams B
// directly from L2 (w1t f16 [u][k]) with NO __syncthreads -> compiler emits
// fine-grained vmcnt and pipelines loads across MFMAs. values read once,
// scores stored directly (no atomics). cvt_values/valf16 removed.

#define B_ 32
#define T_ 2048
#define D_ 512
#define U_ 512
#define M_ (B_ * T_)
#define ASTRIDE 520  // 512 + 8 f16 pad: row stride 260 dwords -> conflict-free

typedef _Float16 half8 __attribute__((ext_vector_type(8)));
typedef float floatx4 __attribute__((ext_vector_type(4)));

__device__ __forceinline__ float fast_tanh(float x) {
  x = fminf(fmaxf(x, -20.f), 20.f);
  const float e = __expf(2.f * x);
  return 1.f - 2.f / (e + 1.f);
}

// ---------------- proj_q = query @ W2 + b2 ----------------
__global__ __launch_bounds__(256) void projq_kernel(
    const float* __restrict__ query, const float* __restrict__ W2,
    const float* __restrict__ b2, float* __restrict__ projq) {
  const int b = blockIdx.x;
  const int u = blockIdx.y * 256 + threadIdx.x;
  __shared__ float q[D_];
  for (int d = threadIdx.x; d < D_; d += 256) q[d] = query[b * D_ + d];
  __syncthreads();
  float acc = 0.f;
#pragma unroll 8
  for (int d = 0; d < D_; ++d) acc += q[d] * W2[d * U_ + u];
  projq[b * U_ + u] = acc + b2[u];
}

// ---------------- W1 [k][u] -> w1t [u][k] f16 ----------------
__global__ __launch_bounds__(256) void prep_w1t(
    const float* __restrict__ W1, _Float16* __restrict__ w1t) {
  __shared__ float t[64][65];
  const int k0 = blockIdx.x * 64, u0 = blockIdx.y * 64;
  const int lu = threadIdx.x & 63;
  const int g = threadIdx.x >> 6;
#pragma unroll
  for (int i = 0; i < 16; ++i) {
    const int row = g * 16 + i;
    t[row][lu] = W1[(long)(k0 + row) * U_ + u0 + lu];
  }
  __syncthreads();
#pragma unroll
  for (int i = 0; i < 16; ++i) {
    const int row = g * 16 + i;
    w1t[(long)(u0 + row) * D_ + k0 + lu] = (_Float16)t[lu][row];
  }
}

// ---------------- scores: fused full-U MFMA + tanh/V, barrier-free loop ----
// Block: 32 rows (m0..m0+31) x all 512 u. 256 threads = 4 waves, wave w
// covers u-slice [w*128, w*128+128) via 2(m) x 8(n) grid of 16x16x32 MFMA.
// A in LDS [32][520] f16 (full K, staged once). B streamed from w1t (L2).
// Frag layouts (verified r2-r5): A[m=lane&15][k=(lane>>4)*8+j],
// B[k=(lane>>4)*8+j][n=lane&15], C[row=(lane>>4)*4+reg][col=lane&15].
__global__ __launch_bounds__(256) void score_fused_kernel(
    const float* __restrict__ values, const _Float16* __restrict__ w1t,
    const float* __restrict__ b1, const float* __restrict__ projq,
    const float* __restrict__ V, float* __restrict__ scores) {
  const int m0 = blockIdx.x * 32;
  const int b = blockIdx.x >> 6;  // 64 blocks per batch
  const int tid = threadIdx.x;
  const int lane = tid & 63;
  const int w = tid >> 6;
  const int wn = w * 128;
  const int ln = lane & 15;
  const int lq = lane >> 4;

  __shared__ alignas(16) _Float16 As[32 * ASTRIDE];
  __shared__ float red[4][32];

  // ---- prologue: stage values[m0..m0+32) fp32 -> f16 LDS (full K) ----
  // flat float4 index f = it*256+tid: row=f>>7, k=(f&127)*4. Global loads
  // fully coalesced (1KB/wave); ds_write_b64 sequential, conflict-free.
  {
    const float* vbase = values + (long)m0 * D_;
#pragma unroll
    for (int it = 0; it < 16; ++it) {
      const int f = it * 256 + tid;
      const int row = f >> 7;
      const int kk = (f & 127) * 4;
      const float4 v = *(const float4*)(vbase + (long)row * D_ + kk);
      _Float16* p = &As[row * ASTRIDE + kk];
      p[0] = (_Float16)v.x;
      p[1] = (_Float16)v.y;
      p[2] = (_Float16)v.z;
      p[3] = (_Float16)v.w;
    }
  }
  __syncthreads();  // the ONLY barrier before the epilogue

  // B base pointers: 8 n-tiles of 16, this wave's u = wn + ni*16 + ln
  const _Float16* bp[8];
#pragma unroll
  for (int ni = 0; ni < 8; ++ni)
    bp[ni] = w1t + (long)(wn + ni * 16 + ln) * D_ + lq * 8;

  floatx4 acc[2][8] = {};

  // ---- barrier-free K-loop ----
  for (int k0 = 0; k0 < D_; k0 += 32) {
    half8 af[2];
#pragma unroll
    for (int mi = 0; mi < 2; ++mi)
      af[mi] = *(const half8*)&As[(mi * 16 + ln) * ASTRIDE + k0 + lq * 8];
    half8 bf[8];
#pragma unroll
    for (int ni = 0; ni < 8; ++ni) bf[ni] = *(const half8*)(bp[ni] + k0);
#pragma unroll
    for (int mi = 0; mi < 2; ++mi)
#pragma unroll
      for (int ni = 0; ni < 8; ++ni)
        acc[mi][ni] = __builtin_amdgcn_mfma_f32_16x16x32_f16(
            af[mi], bf[ni], acc[mi][ni], 0, 0, 0);
  }

  // ---- epilogue: row sums of tanh(c + b1 + projq) * V over this wave's u --
  float pre[8], vv[8];
#pragma unroll
  for (int ni = 0; ni < 8; ++ni) {
    const int u = wn + ni * 16 + ln;
    pre[ni] = b1[u] + projq[b * U_ + u];
    vv[ni] = V[u];
  }
#pragma unroll
  for (int mi = 0; mi < 2; ++mi) {
#pragma unroll
    for (int r = 0; r < 4; ++r) {
      float t = 0.f;
#pragma unroll
      for (int ni = 0; ni < 8; ++ni)
        t += fast_tanh(acc[mi][ni][r] + pre[ni]) * vv[ni];
      t += __shfl_xor(t, 1);
      t += __shfl_xor(t, 2);
      t += __shfl_xor(t, 4);
      t += __shfl_xor(t, 8);
      if (ln == 0) red[w][mi * 16 + lq * 4 + r] = t;  // 4 writers x 8 rows
    }
  }
  __syncthreads();
  if (tid < 32)
    scores[m0 + tid] =
        red[0][tid] + red[1][tid] + red[2][tid] + red[3][tid];
}

// ---------------- softmax over T per batch (+ zero context) ----------------
__global__ __launch_bounds__(256) void softmax_kernel(
    const float* __restrict__ scores, float* __restrict__ weights,
    float* __restrict__ context) {
  ((float2*)context)[blockIdx.x * 256 + threadIdx.x] = make_float2(0.f, 0.f);

  const int b = blockIdx.x;
  const int tid = threadIdx.x;
  float v[8];
  float mx = -INFINITY;
#pragma unroll
  for (int i = 0; i < 8; ++i) {
    v[i] = scores[b * T_ + i * 256 + tid];
    mx = fmaxf(mx, v[i]);
  }
#pragma unroll
  for (int off = 32; off > 0; off >>= 1) mx = fmaxf(mx, __shfl_down(mx, off));
  __shared__ float sm[4], ss[4];
  if ((tid & 63) == 0) sm[tid >> 6] = mx;
  __syncthreads();
  mx = fmaxf(fmaxf(sm[0], sm[1]), fmaxf(sm[2], sm[3]));
  float sum = 0.f;
#pragma unroll
  for (int i = 0; i < 8; ++i) {
    v[i] = __expf(v[i] - mx);
    sum += v[i];
  }
#pragma unroll
  for (int off = 32; off > 0; off >>= 1) sum += __shfl_down(sum, off);
  if ((tid & 63) == 0) ss[tid >> 6] = sum;
  __syncthreads();
  const float inv = 1.f / (ss[0] + ss[1] + ss[2] + ss[3]);
#pragma unroll
  for (int i = 0; i < 8; ++i) weights[b * T_ + i * 256 + tid] = v[i] * inv;
}

// ---------------- context = sum_t w * values ----------------
__global__ __launch_bounds__(256) void context_kernel(
    const float* __restrict__ values, const float* __restrict__ weights,
    float* __restrict__ context) {
  const int b = blockIdx.x;
  const int t0 = blockIdx.y * 64;
  const int tid = threadIdx.x;
  const int g = tid >> 7;
  const int dx = tid & 127;
  __shared__ float wsh[64];
  __shared__ float4 part[128];
  if (tid < 64) wsh[tid] = weights[b * T_ + t0 + tid];
  __syncthreads();
  float4 acc = make_float4(0.f, 0.f, 0.f, 0.f);
  const float4* vp = (const float4*)(values + (long)(b * T_ + t0 + g) * D_) + dx;
#pragma unroll 4
  for (int t = 0; t < 32; ++t) {
    const float4 x = vp[(long)(2 * t) * (D_ / 4)];
    const float ww = wsh[2 * t + g];
    acc.x += ww * x.x; acc.y += ww * x.y; acc.z += ww * x.z; acc.w += ww * x.w;
  }
  if (g == 0) part[dx] = acc;
  __syncthreads();
  if (g == 1) {
    const float4 p = part[dx];
    atomicAdd(&context[b * D_ + dx * 4 + 0], acc.x + p.x);
    atomicAdd(&context[b * D_ + dx * 4 + 1], acc.y + p.y);
    atomicAdd(&context[b * D_ + dx * 4 + 2], acc.z + p.z);
    atomicAdd(&context[b * D_ + dx * 4 + 3], acc.w + p.w);
  }
}

extern "C" void kernel_launch(void* const* d_in, const int* in_sizes, int n_in,
                              void* d_out, int out_size, void* d_ws, size_t ws_size,
                              hipStream_t stream) {
  const float* values = (const float*)d_in[0];
  const float* query = (const float*)d_in[1];
  const float* W1 = (const float*)d_in[2];
  const float* b1 = (const float*)d_in[3];
  const float* W2 = (const float*)d_in[4];
  const float* b2 = (const float*)d_in[5];
  const float* V = (const float*)d_in[6];
  // d_in[7] = bV: unused — softmax is shift-invariant.

  float* out = (float*)d_out;
  float* context = out;            // [32,512]
  float* weights = out + B_ * D_;  // [32,2048]
  float* projq = (float*)d_ws;                                // 64KB
  float* scores = projq + B_ * U_;                            // 256KB
  _Float16* w1t = (_Float16*)((char*)d_ws + 65536 + 262144);  // 512KB
  // needs 832KB of ws; harness ws_size proven >= 68MB in rounds 3-5.

  projq_kernel<<<dim3(B_, U_ / 256), 256, 0, stream>>>(query, W2, b2, projq);
  prep_w1t<<<dim3(D_ / 64, U_ / 64), 256, 0, stream>>>(W1, w1t);
  score_fused_kernel<<<M_ / 32, 256, 0, stream>>>(
      values, w1t, b1, projq, V, scores);
  softmax_kernel<<<B_, 256, 0, stream>>>(scores, weights, context);
  context_kernel<<<dim3(B_, T_ / 64), 256, 0, stream>>>(values, weights, context);
}

// Round 7
// 336.663 us; speedup vs baseline: 1.1880x; 1.1880x over previous
//
#include <hip/hip_runtime.h>
#include <math.h>

// Bahdanau attention, B=32, T=2048, D=512, U=512, fp32 in/out.
// Round 7: (a) score = r5 DMA structure but M-tile 256x128, 32 MFMA/wave/iter
// (launch_bounds(256,2)) - doubles MFMA work per barrier drain, halves B
// traffic vs r5. (b) kernel fusion: prep_fused (cvt+w1t+projq+zeroing) and
// softmax_context (per-block recomputed softmax stats) -> 3 kernels total.

#define B_ 32
#define T_ 2048
#define D_ 512
#define U_ 512
#define M_ (B_ * T_)

typedef _Float16 half8 __attribute__((ext_vector_type(8)));
typedef float floatx4 __attribute__((ext_vector_type(4)));

__device__ __forceinline__ float fast_tanh(float x) {
  x = fminf(fmaxf(x, -20.f), 20.f);
  const float e = __expf(2.f * x);
  return 1.f - 2.f / (e + 1.f);
}

__device__ __forceinline__ void load_lds16(const _Float16* g, _Float16* l) {
  __builtin_amdgcn_global_load_lds(
      (const __attribute__((address_space(1))) void*)g,
      (__attribute__((address_space(3))) void*)l, 16, 0, 0);
}

// ---------------- prep: cvt values->f16 | W1->w1t | projq | zero outs ------
// blocks [0,8192): values fp32 -> valf16 (skipped if do_cvt==0)
// blocks [8192,8256): W1 [k][u] -> w1t [u][k] f16 (64 x 64x64 tiles)
// blocks [8256,8320): projq = query@W2+b2; zero context + scores
__global__ __launch_bounds__(256) void prep_fused(
    const float* __restrict__ values, const float* __restrict__ W1,
    const float* __restrict__ query, const float* __restrict__ W2,
    const float* __restrict__ b2, _Float16* __restrict__ valf16,
    _Float16* __restrict__ w1t, float* __restrict__ projq,
    float* __restrict__ scores, float* __restrict__ context, int do_cvt) {
  __shared__ float sh[64 * 65];
  const int bx = blockIdx.x;
  const int tid = threadIdx.x;
  if (bx < 8192) {
    if (!do_cvt) return;
    const long i = ((long)bx * 256 + tid) * 16;
    const float4 a = *(const float4*)(values + i);
    const float4 b = *(const float4*)(values + i + 4);
    const float4 c = *(const float4*)(values + i + 8);
    const float4 d = *(const float4*)(values + i + 12);
    half8 h0 = {(_Float16)a.x, (_Float16)a.y, (_Float16)a.z, (_Float16)a.w,
                (_Float16)b.x, (_Float16)b.y, (_Float16)b.z, (_Float16)b.w};
    half8 h1 = {(_Float16)c.x, (_Float16)c.y, (_Float16)c.z, (_Float16)c.w,
                (_Float16)d.x, (_Float16)d.y, (_Float16)d.z, (_Float16)d.w};
    *(half8*)(valf16 + i) = h0;
    *(half8*)(valf16 + i + 8) = h1;
  } else if (bx < 8256) {
    const int t = bx - 8192;
    const int k0 = (t >> 3) * 64, u0 = (t & 7) * 64;
    float(*sm)[65] = (float(*)[65])sh;
    const int lu = tid & 63;
    const int g = tid >> 6;
#pragma unroll
    for (int i = 0; i < 16; ++i) {
      const int row = g * 16 + i;
      sm[row][lu] = W1[(long)(k0 + row) * U_ + u0 + lu];
    }
    __syncthreads();
#pragma unroll
    for (int i = 0; i < 16; ++i) {
      const int row = g * 16 + i;
      w1t[(long)(u0 + row) * D_ + k0 + lu] = (_Float16)sm[lu][row];
    }
  } else {
    const int t = bx - 8256;  // [0,64)
    const int gid = t * 256 + tid;
    context[gid] = 0.f;                                     // 16384 floats
    ((float4*)scores)[gid] = make_float4(0.f, 0.f, 0.f, 0.f);  // 65536 floats
    const int b = t >> 1;
    const int u = (t & 1) * 256 + tid;
    for (int d = tid; d < D_; d += 256) sh[d] = query[b * D_ + d];
    __syncthreads();
    float acc = 0.f;
#pragma unroll 8
    for (int d = 0; d < D_; ++d) acc += sh[d] * W2[d * U_ + u];
    projq[b * U_ + u] = acc + b2[u];
  }
}

// ---------------- scores: DMA-staged f16 MFMA, 256x128 tile ----------------
// Grid (M/256, U/128). 256 threads = 4 waves 2x2; wave = 128m x 64u via
// 8x4 grid of 16x16x32 MFMA (acc 128 regs; launch_bounds(256,2)).
// A: valf16 -> LDS via global_load_lds, rows 32 f16 = 64B = 4 chunks of 16B,
// global chunk c of row r stored at slot c^(r&3) -> frag reads spread banks.
// B: direct global half8 from w1t [u][k] (L2-resident).
// Frag layouts (verified r2-r6): A[m=lane&15][k=(lane>>4)*8+j],
// B[k=(lane>>4)*8+j][n=lane&15], C[row=(lane>>4)*4+reg][col=lane&15].
__global__ __launch_bounds__(256, 2) void score_dma_kernel(
    const _Float16* __restrict__ valf16, const _Float16* __restrict__ w1t,
    const float* __restrict__ b1, const float* __restrict__ projq,
    const float* __restrict__ V, float* __restrict__ scores) {
  const int m0 = blockIdx.x * 256;
  const int b = blockIdx.x >> 3;  // 2048/256 = 8 row-blocks per batch
  const int u0 = blockIdx.y * 128;
  const int tid = threadIdx.x;
  const int lane = tid & 63;
  const int w = tid >> 6;
  const int wm = (w & 1) * 128;
  const int wn = u0 + (w >> 1) * 64;
  const int ln = lane & 15;
  const int lq = lane >> 4;

  __shared__ alignas(16) _Float16 As[256 * 32];  // [m][32k] packed, swizzled
  __shared__ float red[2][256];

  // DMA: wave w stages rows [w*64, w*64+64) in 4 groups of 16 rows.
  const int rl = lane >> 2;                       // 0..15 within group
  const int cg = (lane & 3) ^ (rl & 3);           // swizzled global chunk
  const _Float16* gA[4];
  _Float16* lA[4];
#pragma unroll
  for (int j = 0; j < 4; ++j) {
    const int r = w * 64 + j * 16 + rl;
    gA[j] = valf16 + (long)(m0 + r) * D_ + cg * 8;
    lA[j] = &As[(w * 64 + j * 16) * 32];
  }

  const _Float16* bp[4];
#pragma unroll
  for (int ni = 0; ni < 4; ++ni)
    bp[ni] = w1t + (long)(wn + ni * 16 + ln) * D_ + lq * 8;

  const int aswz = (lq ^ (ln & 3)) * 8;  // swizzled frag k-slot

  floatx4 acc[8][4] = {};

  for (int k0 = 0; k0 < D_; k0 += 32) {
#pragma unroll
    for (int j = 0; j < 4; ++j) load_lds16(gA[j] + k0, lA[j]);
    half8 bf[4];
#pragma unroll
    for (int ni = 0; ni < 4; ++ni) bf[ni] = *(const half8*)(bp[ni] + k0);
    __syncthreads();  // drains DMA + bf loads
    half8 af[8];
#pragma unroll
    for (int mi = 0; mi < 8; ++mi)
      af[mi] = *(const half8*)&As[(wm + mi * 16 + ln) * 32 + aswz];
#pragma unroll
    for (int mi = 0; mi < 8; ++mi)
#pragma unroll
      for (int ni = 0; ni < 4; ++ni)
        acc[mi][ni] = __builtin_amdgcn_mfma_f32_16x16x32_f16(
            af[mi], bf[ni], acc[mi][ni], 0, 0, 0);
    __syncthreads();  // LDS consumed before next DMA overwrites
  }

  // Epilogue: row partials of tanh(c + b1 + projq) * V over this wave's 64 u
  float pre[4], vv[4];
#pragma unroll
  for (int ni = 0; ni < 4; ++ni) {
    const int u = wn + ni * 16 + ln;
    pre[ni] = b1[u] + projq[b * U_ + u];
    vv[ni] = V[u];
  }
#pragma unroll
  for (int mi = 0; mi < 8; ++mi) {
#pragma unroll
    for (int r = 0; r < 4; ++r) {
      float t = 0.f;
#pragma unroll
      for (int ni = 0; ni < 4; ++ni)
        t += fast_tanh(acc[mi][ni][r] + pre[ni]) * vv[ni];
      t += __shfl_xor(t, 1);
      t += __shfl_xor(t, 2);
      t += __shfl_xor(t, 4);
      t += __shfl_xor(t, 8);
      if (ln == 0) red[w >> 1][wm + mi * 16 + lq * 4 + r] = t;
    }
  }
  __syncthreads();
  atomicAdd(scores + m0 + tid, red[0][tid] + red[1][tid]);
}

// ---------------- fallback score (r4 structure) if ws < 68MB ---------------
__global__ __launch_bounds__(256) void score_lds_kernel(
    const float* __restrict__ values, const _Float16* __restrict__ w1t,
    const float* __restrict__ b1, const float* __restrict__ projq,
    const float* __restrict__ V, float* __restrict__ scores) {
  const int m0 = blockIdx.x * 128;
  const int u0 = blockIdx.y * 128;
  const int b = blockIdx.x >> 4;
  const int tid = threadIdx.x;
  const int lane = tid & 63;
  const int w = tid >> 6;
  const int wm = (w & 1) * 64;
  const int wn = (w >> 1) * 64;
  const int ln = lane & 15;
  const int lq = lane >> 4;
  __shared__ alignas(16) _Float16 As[128 * 40];
  const int srow = tid >> 1;
  const int skoff = (tid & 1) * 16;
  const float* aptr = values + (long)(m0 + srow) * D_ + skoff;
  _Float16* awr = &As[srow * 40 + skoff];
  const _Float16* bBase = w1t + (long)(u0 + wn + ln) * D_ + lq * 8;
  floatx4 acc[4][4] = {};
  for (int k0 = 0; k0 < D_; k0 += 32) {
    const float4 a0 = *(const float4*)(aptr + k0);
    const float4 a1 = *(const float4*)(aptr + k0 + 4);
    const float4 a2 = *(const float4*)(aptr + k0 + 8);
    const float4 a3 = *(const float4*)(aptr + k0 + 12);
    half8 bf[4];
#pragma unroll
    for (int ni = 0; ni < 4; ++ni)
      bf[ni] = *(const half8*)(bBase + (long)ni * 16 * D_ + k0);
    half8 h0 = {(_Float16)a0.x, (_Float16)a0.y, (_Float16)a0.z, (_Float16)a0.w,
                (_Float16)a1.x, (_Float16)a1.y, (_Float16)a1.z, (_Float16)a1.w};
    half8 h1 = {(_Float16)a2.x, (_Float16)a2.y, (_Float16)a2.z, (_Float16)a2.w,
                (_Float16)a3.x, (_Float16)a3.y, (_Float16)a3.z, (_Float16)a3.w};
    *(half8*)awr = h0;
    *(half8*)(awr + 8) = h1;
    __syncthreads();
    half8 af[4];
#pragma unroll
    for (int i = 0; i < 4; ++i)
      af[i] = *(const half8*)&As[(wm + i * 16 + ln) * 40 + lq * 8];
#pragma unroll
    for (int mi = 0; mi < 4; ++mi)
#pragma unroll
      for (int ni = 0; ni < 4; ++ni)
        acc[mi][ni] = __builtin_amdgcn_mfma_f32_16x16x32_f16(
            af[mi], bf[ni], acc[mi][ni], 0, 0, 0);
    __syncthreads();
  }
  float pre[4], vv[4];
#pragma unroll
  for (int ni = 0; ni < 4; ++ni) {
    const int u = u0 + wn + ni * 16 + ln;
    pre[ni] = b1[u] + projq[b * U_ + u];
    vv[ni] = V[u];
  }
#pragma unroll
  for (int mi = 0; mi < 4; ++mi) {
#pragma unroll
    for (int r = 0; r < 4; ++r) {
      float t = 0.f;
#pragma unroll
      for (int ni = 0; ni < 4; ++ni)
        t += fast_tanh(acc[mi][ni][r] + pre[ni]) * vv[ni];
      t += __shfl_xor(t, 1);
      t += __shfl_xor(t, 2);
      t += __shfl_xor(t, 4);
      t += __shfl_xor(t, 8);
      if (ln == mi * 4 + r)
        atomicAdd(scores + m0 + wm + mi * 16 + lq * 4 + r, t);
    }
  }
}

// ---------------- fused softmax + context ----------------
// Grid (B, T/64). Every block recomputes batch-b softmax stats from scores
// (deterministic -> consistent across blocks), writes its 64-row weight
// slice, accumulates its context partial via atomics.
__global__ __launch_bounds__(256) void softmax_context_kernel(
    const float* __restrict__ scores, const float* __restrict__ values,
    float* __restrict__ weights, float* __restrict__ context) {
  const int b = blockIdx.x;
  const int t0 = blockIdx.y * 64;
  const int tid = threadIdx.x;

  // full-batch softmax stats
  float v[8];
  float mx = -INFINITY;
#pragma unroll
  for (int i = 0; i < 8; ++i) {
    v[i] = scores[b * T_ + i * 256 + tid];
    mx = fmaxf(mx, v[i]);
  }
#pragma unroll
  for (int off = 32; off > 0; off >>= 1) mx = fmaxf(mx, __shfl_down(mx, off));
  __shared__ float sm[4], ss[4];
  if ((tid & 63) == 0) sm[tid >> 6] = mx;
  __syncthreads();
  mx = fmaxf(fmaxf(sm[0], sm[1]), fmaxf(sm[2], sm[3]));
  float sum = 0.f;
#pragma unroll
  for (int i = 0; i < 8; ++i) sum += __expf(v[i] - mx);
#pragma unroll
  for (int off = 32; off > 0; off >>= 1) sum += __shfl_down(sum, off);
  if ((tid & 63) == 0) ss[tid >> 6] = sum;
  __syncthreads();
  const float inv = 1.f / (ss[0] + ss[1] + ss[2] + ss[3]);

  // weights for our 64 rows
  __shared__ float wsh[64];
  if (tid < 64) {
    const float ww = __expf(scores[b * T_ + t0 + tid] - mx) * inv;
    wsh[tid] = ww;
    weights[b * T_ + t0 + tid] = ww;
  }
  __syncthreads();

  // context partial
  const int g = tid >> 7;
  const int dx = tid & 127;
  __shared__ float4 part[128];
  float4 acc = make_float4(0.f, 0.f, 0.f, 0.f);
  const float4* vp = (const float4*)(values + (long)(b * T_ + t0 + g) * D_) + dx;
#pragma unroll 4
  for (int t = 0; t < 32; ++t) {
    const float4 x = vp[(long)(2 * t) * (D_ / 4)];
    const float ww = wsh[2 * t + g];
    acc.x += ww * x.x; acc.y += ww * x.y; acc.z += ww * x.z; acc.w += ww * x.w;
  }
  if (g == 0) part[dx] = acc;
  __syncthreads();
  if (g == 1) {
    const float4 p = part[dx];
    atomicAdd(&context[b * D_ + dx * 4 + 0], acc.x + p.x);
    atomicAdd(&context[b * D_ + dx * 4 + 1], acc.y + p.y);
    atomicAdd(&context[b * D_ + dx * 4 + 2], acc.z + p.z);
    atomicAdd(&context[b * D_ + dx * 4 + 3], acc.w + p.w);
  }
}

extern "C" void kernel_launch(void* const* d_in, const int* in_sizes, int n_in,
                              void* d_out, int out_size, void* d_ws, size_t ws_size,
                              hipStream_t stream) {
  const float* values = (const float*)d_in[0];
  const float* query = (const float*)d_in[1];
  const float* W1 = (const float*)d_in[2];
  const float* b1 = (const float*)d_in[3];
  const float* W2 = (const float*)d_in[4];
  const float* b2 = (const float*)d_in[5];
  const float* V = (const float*)d_in[6];
  // d_in[7] = bV: unused — softmax is shift-invariant.

  float* out = (float*)d_out;
  float* context = out;            // [32,512]
  float* weights = out + B_ * D_;  // [32,2048]
  float* projq = (float*)d_ws;                                // 64KB
  float* scores = projq + B_ * U_;                            // 256KB
  _Float16* w1t = (_Float16*)((char*)d_ws + 65536 + 262144);  // 512KB
  _Float16* valf16 = (_Float16*)((char*)d_ws + 851968);       // 64MB

  const int dma = ws_size >= (size_t)851968 + (size_t)M_ * D_ * 2;

  prep_fused<<<8320, 256, 0, stream>>>(values, W1, query, W2, b2, valf16, w1t,
                                       projq, scores, context, dma);
  if (dma) {
    score_dma_kernel<<<dim3(M_ / 256, U_ / 128), 256, 0, stream>>>(
        valf16, w1t, b1, projq, V, scores);
  } else {
    score_lds_kernel<<<dim3(M_ / 128, U_ / 128), 256, 0, stream>>>(
        values, w1t, b1, projq, V, scores);
  }
  softmax_context_kernel<<<dim3(B_, T_ / 64), 256, 0, stream>>>(
      scores, values, weights, context);
}